// Round 8
// baseline (346.729 us; speedup 1.0000x reference)
//
#include <hip/hip_runtime.h>
#include <hip/hip_fp16.h>

#define NB   256   // dst buckets (512 nodes each), bucket = dst >> 9
#define NBLK 256   // blocks in phases A/C
#define BSH  9

typedef _Float16 f16;
typedef _Float16 half8 __attribute__((ext_vector_type(8)));
typedef __fp16 pk16x2 __attribute__((ext_vector_type(2)));  // cvt_pkrtz return type
typedef float f32x4 __attribute__((ext_vector_type(4)));

// ============================================================
// Prep: transpose W [k][n] f32 -> Wt [n][k] f16 (and lin_w -> LWt).
// ============================================================
__global__ void k_prep(const float* __restrict__ W, const float* __restrict__ LW,
                       f16* __restrict__ Wt, f16* __restrict__ LWt)
{
    int n = blockIdx.x & 127;
    const float* src = (blockIdx.x < 128) ? W : LW;
    f16* dst = (blockIdx.x < 128) ? Wt : LWt;
    int k = threadIdx.x;  // 128 threads
    dst[n * 128 + k] = (f16)src[k * 128 + n];
}

// ============================================================
// MFMA GEMM 1: H = x @ W (f32 in -> fp16 compute, f32 acc, fp16 out)
// + attention-logit epilogue. Tile 64x128, 4 waves.
// Frag maps (m89/m120-verified): A[m=lane&15][k=quad*8+j],
// B[k=quad*8+j][n=lane&15], C/D col=lane&15 row=quad*4+reg.
// ============================================================
__global__ __launch_bounds__(256) void k_gemm_att(
    const float* __restrict__ A, const f16* __restrict__ Wt,
    const float* __restrict__ att_s, const float* __restrict__ att_d,
    f16* __restrict__ Hh, float* __restrict__ as_out, float* __restrict__ ad_out,
    int M)
{
    __shared__ __align__(16) f16 as_lds[64 * 136];
    int t = threadIdx.x;
    int row0 = blockIdx.x * 64;

    // Stage A: f32 -> f16 packed, [m][k] stride 136
    {
        int r = t >> 2, kq = (t & 3) * 32;
        const float* ap = A + (size_t)(row0 + r) * 128 + kq;
        bool valid = (row0 + r) < M;
        pk16x2 hb[16];
#pragma unroll
        for (int j = 0; j < 8; ++j) {
            float4 v = valid ? *(const float4*)(ap + j * 4) : make_float4(0.f, 0.f, 0.f, 0.f);
            hb[2 * j]     = __builtin_amdgcn_cvt_pkrtz(v.x, v.y);
            hb[2 * j + 1] = __builtin_amdgcn_cvt_pkrtz(v.z, v.w);
        }
        f16* dst = as_lds + r * 136 + kq;
#pragma unroll
        for (int j = 0; j < 4; ++j) *(float4*)(dst + j * 8) = ((float4*)hb)[j];
    }
    __syncthreads();

    int w = t >> 6, ln = t & 63;
    int rr = (w & 1) * 32;
    int cc = (w >> 1) * 64;
    int q = ln >> 4, m = ln & 15;

    f32x4 acc[2][4];
#pragma unroll
    for (int i = 0; i < 2; ++i)
#pragma unroll
        for (int j = 0; j < 4; ++j) acc[i][j] = (f32x4){0.f, 0.f, 0.f, 0.f};

    const f16* wp = Wt + (size_t)(cc + m) * 128 + q * 8;
#pragma unroll
    for (int ks = 0; ks < 4; ++ks) {
        int k0 = ks * 32 + q * 8;
        half8 a0 = *(const half8*)(as_lds + (rr + m) * 136 + k0);
        half8 a1 = *(const half8*)(as_lds + (rr + 16 + m) * 136 + k0);
        half8 bf[4];
#pragma unroll
        for (int j = 0; j < 4; ++j)
            bf[j] = *(const half8*)(wp + j * 16 * 128 + ks * 32);
#pragma unroll
        for (int j = 0; j < 4; ++j) {
            acc[0][j] = __builtin_amdgcn_mfma_f32_16x16x32_f16(a0, bf[j], acc[0][j], 0, 0, 0);
            acc[1][j] = __builtin_amdgcn_mfma_f32_16x16x32_f16(a1, bf[j], acc[1][j], 0, 0, 0);
        }
    }
    __syncthreads();
    // acc -> epilogue tile (reuse as_lds) [row][col] f16 stride 136
#pragma unroll
    for (int i = 0; i < 2; ++i)
#pragma unroll
        for (int j = 0; j < 4; ++j)
#pragma unroll
            for (int g = 0; g < 4; ++g)
                as_lds[(rr + i * 16 + q * 4 + g) * 136 + cc + j * 16 + m] = (f16)acc[i][j][g];
    __syncthreads();
    // coalesced H write
    {
        int r = t >> 2, cq = (t & 3) * 32;
        if (row0 + r < M) {
            float4 o0 = *(const float4*)(as_lds + r * 136 + cq);
            float4 o1 = *(const float4*)(as_lds + r * 136 + cq + 8);
            float4 o2 = *(const float4*)(as_lds + r * 136 + cq + 16);
            float4 o3 = *(const float4*)(as_lds + r * 136 + cq + 24);
            float4* hp = (float4*)(Hh + (size_t)(row0 + r) * 128 + cq);
            hp[0] = o0; hp[1] = o1; hp[2] = o2; hp[3] = o3;
        }
    }
    // attention dots: wave w rows w*16..+15; lane (q,m): row w*16+m, head q
    {
        int rl = w * 16 + m;
        int head = q;
        float ds = 0.f, dd = 0.f;
#pragma unroll
        for (int ch = 0; ch < 4; ++ch) {
            half8 hv = *(const half8*)(as_lds + rl * 136 + head * 32 + ch * 8);
            float4 s0 = *(const float4*)(att_s + head * 32 + ch * 8);
            float4 s1 = *(const float4*)(att_s + head * 32 + ch * 8 + 4);
            float4 d0 = *(const float4*)(att_d + head * 32 + ch * 8);
            float4 d1 = *(const float4*)(att_d + head * 32 + ch * 8 + 4);
            ds += (float)hv[0] * s0.x + (float)hv[1] * s0.y + (float)hv[2] * s0.z + (float)hv[3] * s0.w
                + (float)hv[4] * s1.x + (float)hv[5] * s1.y + (float)hv[6] * s1.z + (float)hv[7] * s1.w;
            dd += (float)hv[0] * d0.x + (float)hv[1] * d0.y + (float)hv[2] * d0.z + (float)hv[3] * d0.w
                + (float)hv[4] * d1.x + (float)hv[5] * d1.y + (float)hv[6] * d1.z + (float)hv[7] * d1.w;
        }
        if (row0 + rl < M) {
            as_out[(row0 + rl) * 4 + head] = ds;
            ad_out[(row0 + rl) * 4 + head] = dd;
        }
    }
}

// ============================================================
// CSR build, atomic-free at global scope (counting sort, 2 levels).
// binned entry packed: src (17b) | dst-low-9 << 17  (N < 2^17).
// ============================================================

__global__ __launch_bounds__(256) void k_ph_hist(
    const int* __restrict__ dst, int* __restrict__ bh, int E, int chunk)
{
    __shared__ int hist[NB];
    int t = threadIdx.x;
    hist[t] = 0;
    __syncthreads();
    int e0 = blockIdx.x * chunk;
    int e1 = min(e0 + chunk, E);
    for (int e = e0 + t; e < e1; e += 256)
        atomicAdd(&hist[dst[e] >> BSH], 1);
    __syncthreads();
    bh[t * NBLK + blockIdx.x] = hist[t];
}

__global__ __launch_bounds__(1024) void k_ph_scan(int* __restrict__ bh)
{
    __shared__ int sd[1024];
    const int per = (NB * NBLK) / 1024;  // 64
    int t = threadIdx.x;
    int base = t * per;
    int loc[per];
    int sum = 0;
#pragma unroll
    for (int j = 0; j < per; ++j) { loc[j] = bh[base + j]; sum += loc[j]; }
    sd[t] = sum;
    __syncthreads();
    for (int o = 1; o < 1024; o <<= 1) {
        int x = (t >= o) ? sd[t - o] : 0;
        __syncthreads();
        sd[t] += x;
        __syncthreads();
    }
    int run = sd[t] - sum;
#pragma unroll
    for (int j = 0; j < per; ++j) { bh[base + j] = run; run += loc[j]; }
}

__global__ __launch_bounds__(256) void k_ph_bin(
    const int* __restrict__ ei, const int* __restrict__ bh,
    int* __restrict__ binned, int E, int chunk)
{
    __shared__ int boff[NB];
    int t = threadIdx.x;
    boff[t] = bh[t * NBLK + blockIdx.x];
    __syncthreads();
    int e0 = blockIdx.x * chunk;
    int e1 = min(e0 + chunk, E);
    for (int e = e0 + t; e < e1; e += 256) {
        int s = ei[e];
        int d = ei[E + e];
        int p = atomicAdd(&boff[d >> BSH], 1);  // LDS atomic
        binned[p] = s | ((d & ((1 << BSH) - 1)) << 17);
    }
}

__global__ __launch_bounds__(256) void k_ph_csr(
    const int* __restrict__ binned, const int* __restrict__ bh,
    int* __restrict__ csr, int* __restrict__ off, int* __restrict__ deg,
    int N, int E)
{
    __shared__ int cnt[512], loff[512], sd[256];
    int b = blockIdx.x;
    int lo = b << BSH;
    if (lo >= N) return;
    int t = threadIdx.x;
    int seg = bh[b * NBLK];
    int segend = (b + 1 < NB) ? bh[(b + 1) * NBLK] : E;
    int len = segend - seg;
    cnt[t] = 0; cnt[t + 256] = 0;
    __syncthreads();
    for (int i = t; i < len; i += 256)
        atomicAdd(&cnt[(unsigned)binned[seg + i] >> 17], 1);
    __syncthreads();
    int a0 = cnt[2 * t], a1 = cnt[2 * t + 1];
    int s = a0 + a1;
    sd[t] = s;
    __syncthreads();
    for (int o = 1; o < 256; o <<= 1) {
        int x = (t >= o) ? sd[t - o] : 0;
        __syncthreads();
        sd[t] += x;
        __syncthreads();
    }
    int ex = sd[t] - s;
    loff[2 * t] = ex;
    loff[2 * t + 1] = ex + a0;
    int n0 = lo + 2 * t;
    if (n0 < N)     { off[n0] = seg + ex;          deg[n0] = a0; }
    if (n0 + 1 < N) { off[n0 + 1] = seg + ex + a0; deg[n0 + 1] = a1; }
    __syncthreads();
    for (int i = t; i < len; i += 256) {
        int v = binned[seg + i];
        int p = atomicAdd(&loff[(unsigned)v >> 17], 1);  // LDS atomic
        csr[seg + p] = v & 0x1ffff;
    }
}

// ============================================================
// FUSED gather + GEMM2: block owns 64 dst nodes. Wave w gathers its 16
// nodes' P rows straight into the GEMM A-tile in LDS (no P round-trip),
// then the block runs MFMA(P, LWt) + bias + relu + f32 store.
// Inner loop reads one packed int2 {half2 weight, src} per edge.
// ============================================================
__global__ __launch_bounds__(256) void k_gather_gemm(
    const __half* __restrict__ Hh, const float* __restrict__ as_,
    const float* __restrict__ ad_, const int* __restrict__ off,
    const int* __restrict__ deg, const int* __restrict__ csr,
    const f16* __restrict__ LWt, const float* __restrict__ bias,
    float* __restrict__ Out, int N)
{
    __shared__ __align__(16) f16 p_lds[64 * 136];
    __shared__ int2 ews[4][4][68];   // [wave][head][edge]: {half2 w, src}
    int t = threadIdx.x;
    int w = t >> 6, lane = t & 63;
    int row0 = blockIdx.x * 64;

    int g = lane >> 4;        // edge sub-slot 0..3
    int li = lane & 15;       // channel group: channels li*8..+7
    int hh = li >> 2;         // head of this channel group

    // ---- gather phase: wave w -> local rows w*16 .. w*16+15 ----
    for (int nl = 0; nl < 16; ++nl) {
        int ln = w * 16 + nl;
        int n = row0 + ln;
        if (n >= N) break;
        int dg = deg[n];
        int base = off[n];
        float4 adn = *(const float4*)(ad_ + (size_t)n * 4);
        float s0 = 0.f, s1 = 0.f, s2 = 0.f, s3 = 0.f;
        float acc[8] = {0.f, 0.f, 0.f, 0.f, 0.f, 0.f, 0.f, 0.f};

        for (int c0 = 0; c0 < dg; c0 += 64) {
            int cnt = min(64, dg - c0);
            {   // weight phase: 1 edge/lane, zero-pad
                int idx = c0 + lane;
                int se = csr[base + min(idx, dg - 1)];
                float4 as = *(const float4*)(as_ + (size_t)se * 4);
                float e0 = as.x + adn.x, e1 = as.y + adn.y;
                float e2 = as.z + adn.z, e3 = as.w + adn.w;
                e0 = fmaxf(e0, 0.2f * e0); e1 = fmaxf(e1, 0.2f * e1);
                e2 = fmaxf(e2, 0.2f * e2); e3 = fmaxf(e3, 0.2f * e3);
                float x0 = __expf(e0), x1 = __expf(e1);
                float x2 = __expf(e2), x3 = __expf(e3);
                if (idx >= dg) { x0 = x1 = x2 = x3 = 0.f; }
                s0 += x0; s1 += x1; s2 += x2; s3 += x3;
                __half2 w0 = __float2half2_rn(x0), w1 = __float2half2_rn(x1);
                __half2 w2h = __float2half2_rn(x2), w3 = __float2half2_rn(x3);
                ews[w][0][lane] = make_int2(*(int*)&w0, se);
                ews[w][1][lane] = make_int2(*(int*)&w1, se);
                ews[w][2][lane] = make_int2(*(int*)&w2h, se);
                ews[w][3][lane] = make_int2(*(int*)&w3, se);
            }
            __asm__ volatile("s_waitcnt lgkmcnt(0)" ::: "memory");
            int iters = (cnt + 3) >> 2;
            __half2 ah[4];
            ah[0] = ah[1] = ah[2] = ah[3] = __float2half2_rn(0.f);
            for (int ii = 0; ii < iters; ++ii) {
                int j = ii * 4 + g;          // pad edges have w=0
                int2 e = ews[w][hh][j];
                __half2 w2 = *(__half2*)&e.x;
                float4 raw = *(const float4*)(Hh + (size_t)e.y * 128 + li * 8);
                __half2* ph = (__half2*)&raw;
                ah[0] = __hfma2(ph[0], w2, ah[0]);
                ah[1] = __hfma2(ph[1], w2, ah[1]);
                ah[2] = __hfma2(ph[2], w2, ah[2]);
                ah[3] = __hfma2(ph[3], w2, ah[3]);
                if ((ii & 7) == 7) {  // f32 flush every 8 edges/lane
#pragma unroll
                    for (int k = 0; k < 4; ++k) {
                        float2 f = __half22float2(ah[k]);
                        acc[2 * k] += f.x; acc[2 * k + 1] += f.y;
                        ah[k] = __float2half2_rn(0.f);
                    }
                }
            }
#pragma unroll
            for (int k = 0; k < 4; ++k) {
                float2 f = __half22float2(ah[k]);
                acc[2 * k] += f.x; acc[2 * k + 1] += f.y;
            }
            __asm__ volatile("s_waitcnt lgkmcnt(0)" ::: "memory");
        }

        // softmax denominators
#pragma unroll
        for (int o = 1; o < 64; o <<= 1) {
            s0 += __shfl_xor(s0, o);
            s1 += __shfl_xor(s1, o);
            s2 += __shfl_xor(s2, o);
            s3 += __shfl_xor(s3, o);
        }
        // combine the 4 edge sub-slots
#pragma unroll
        for (int o = 16; o < 64; o <<= 1)
#pragma unroll
            for (int c = 0; c < 8; ++c) acc[c] += __shfl_xor(acc[c], o);

        float sh = (hh == 0) ? s0 : (hh == 1) ? s1 : (hh == 2) ? s2 : s3;
        float inv = 1.f / (sh + 1e-16f);
        if (g == 0) {
            pk16x2 o4[4];
#pragma unroll
            for (int k = 0; k < 4; ++k)
                o4[k] = __builtin_amdgcn_cvt_pkrtz(acc[2 * k] * inv, acc[2 * k + 1] * inv);
            *(float4*)(p_lds + ln * 136 + li * 8) = *(float4*)o4;
        }
    }
    __syncthreads();

    // ---- GEMM2 phase: Out = relu(P @ lin_w + b) ----
    int rr = (w & 1) * 32;
    int cc = (w >> 1) * 64;
    int q = lane >> 4, m = lane & 15;

    f32x4 gacc[2][4];
#pragma unroll
    for (int i = 0; i < 2; ++i)
#pragma unroll
        for (int j = 0; j < 4; ++j) gacc[i][j] = (f32x4){0.f, 0.f, 0.f, 0.f};

    const f16* wp = LWt + (size_t)(cc + m) * 128 + q * 8;
#pragma unroll
    for (int ks = 0; ks < 4; ++ks) {
        int k0 = ks * 32 + q * 8;
        half8 a0 = *(const half8*)(p_lds + (rr + m) * 136 + k0);
        half8 a1 = *(const half8*)(p_lds + (rr + 16 + m) * 136 + k0);
        half8 bf[4];
#pragma unroll
        for (int j = 0; j < 4; ++j)
            bf[j] = *(const half8*)(wp + j * 16 * 128 + ks * 32);
#pragma unroll
        for (int j = 0; j < 4; ++j) {
            gacc[0][j] = __builtin_amdgcn_mfma_f32_16x16x32_f16(a0, bf[j], gacc[0][j], 0, 0, 0);
            gacc[1][j] = __builtin_amdgcn_mfma_f32_16x16x32_f16(a1, bf[j], gacc[1][j], 0, 0, 0);
        }
    }
    float bv[4];
#pragma unroll
    for (int j = 0; j < 4; ++j) bv[j] = bias[cc + j * 16 + m];
#pragma unroll
    for (int i = 0; i < 2; ++i)
#pragma unroll
        for (int g2 = 0; g2 < 4; ++g2) {
            int row = row0 + rr + i * 16 + q * 4 + g2;
            if (row < N) {
#pragma unroll
                for (int j = 0; j < 4; ++j)
                    Out[(size_t)row * 128 + cc + j * 16 + m] = fmaxf(gacc[i][j][g2] + bv[j], 0.f);
            }
        }
}

// ============================================================

extern "C" void kernel_launch(void* const* d_in, const int* in_sizes, int n_in,
                              void* d_out, int out_size, void* d_ws, size_t ws_size,
                              hipStream_t stream)
{
    const float* x     = (const float*)d_in[0];
    const int*   ei    = (const int*)d_in[1];
    const float* W     = (const float*)d_in[2];
    const float* att_s = (const float*)d_in[3];
    const float* att_d = (const float*)d_in[4];
    const float* lin_w = (const float*)d_in[5];
    const float* lin_b = (const float*)d_in[6];
    float* out = (float*)d_out;
    int N = in_sizes[0] / 128;
    int E = in_sizes[1] / 2;

    char* p = (char*)d_ws;
    auto alloc = [&](size_t bytes) { char* r = p; p += (bytes + 255) & ~(size_t)255; return r; };
    f16*    Hh   = (f16*)alloc((size_t)N * 128 * 2);
    f16*    Wt   = (f16*)alloc(128 * 128 * 2);
    f16*    LWt  = (f16*)alloc(128 * 128 * 2);
    float*  AS   = (float*)alloc((size_t)N * 4 * 4);
    float*  AD   = (float*)alloc((size_t)N * 4 * 4);
    int*    deg  = (int*)alloc((size_t)N * 4);
    int*    off  = (int*)alloc((size_t)N * 4);
    int*    csr  = (int*)alloc((size_t)E * 4);
    int*    binned = (int*)alloc((size_t)E * 4);
    int*    bh   = (int*)alloc((size_t)NB * NBLK * 4);

    int chunk = (E + NBLK - 1) / NBLK;
    int mb = (N + 63) / 64;
    k_prep<<<256, 128, 0, stream>>>(W, lin_w, Wt, LWt);
    k_gemm_att<<<mb, 256, 0, stream>>>(x, Wt, att_s, att_d, Hh, AS, AD, N);
    k_ph_hist<<<NBLK, 256, 0, stream>>>(ei + E, bh, E, chunk);
    k_ph_scan<<<1, 1024, 0, stream>>>(bh);
    k_ph_bin<<<NBLK, 256, 0, stream>>>(ei, bh, binned, E, chunk);
    k_ph_csr<<<NB, 256, 0, stream>>>(binned, bh, csr, off, deg, N, E);
    k_gather_gemm<<<mb, 256, 0, stream>>>((const __half*)Hh, AS, AD, off, deg, csr,
                                          LWt, lin_b, out, N);
}